// Round 3
// baseline (289.275 us; speedup 1.0000x reference)
//
#include <hip/hip_runtime.h>
#include <stdint.h>

#define NB 512      // batch
#define NFEAT 8192
#define NG 512      // groups
#define GG 64       // gather size / K
#define DD 128      // out features per group

typedef float f32x4 __attribute__((ext_vector_type(4)));

// xT[c][b] = x[b][c], f32, via LDS tile transpose (coalesced both sides)
__global__ __launch_bounds__(256) void transpose_x(const float* __restrict__ x,
                                                   float* __restrict__ xT) {
  __shared__ float t[64][65];
  const int c0 = blockIdx.x * 64;
  const int b0 = blockIdx.y * 64;
  const int tid = threadIdx.x;
  const int col = tid & 63;
  const int rg = tid >> 6;            // 0..3
  #pragma unroll
  for (int r = 0; r < 16; ++r) {
    int row = rg * 16 + r;            // b-local
    t[col][row] = x[(size_t)(b0 + row) * NFEAT + c0 + col];
  }
  __syncthreads();
  #pragma unroll
  for (int r = 0; r < 16; ++r) {
    int crow = rg * 16 + r;           // c-local
    xT[(size_t)(c0 + crow) * NB + b0 + col] = t[crow][col];
  }
}

// One thread = (b, d-half of group n). 128 threads/block = 2 waves (dh 0/1), 64 b rows.
// Inner loop software-pipelined in 8-g chunks: prefetch next 8 idx (s_load) + 8 xT
// (coalesced vector loads) under 512 FMAs of the current chunk.
__global__ __launch_bounds__(128) void lc_f32(
    const float* __restrict__ xT,
    const float* __restrict__ W,
    const int* __restrict__ idx,
    const float* __restrict__ bias,
    const float* __restrict__ gamma,
    const float* __restrict__ beta,
    float* __restrict__ out) {
  __shared__ float part[2][64][2];    // 1 KiB: LN cross-wave partials

  const int n = blockIdx.x;
  const int b0 = blockIdx.y * 64;
  const int tid = threadIdx.x;
  const int lane = tid & 63;
  const int dh = tid >> 6;            // 0/1 (wave-uniform by construction)
  const int b = b0 + lane;

  const int* idxn = idx + n * GG;
  const float* wbase = W + (size_t)n * (GG * DD) + dh * 64;

  float acc[64];
  #pragma unroll
  for (int j = 0; j < 64; ++j) acc[j] = 0.f;

  // pipeline prologue: chunk 0
  int   cc[8];
  float xv[8];
  #pragma unroll
  for (int j = 0; j < 8; ++j) cc[j] = idxn[j];                    // uniform -> s_load
  #pragma unroll
  for (int j = 0; j < 8; ++j) xv[j] = xT[(size_t)cc[j] * NB + b]; // coalesced

  for (int gc = 0; gc < 8; ++gc) {    // dynamic loop: keeps icache small
    float xn[8];
    if (gc < 7) {
      int cn[8];
      #pragma unroll
      for (int j = 0; j < 8; ++j) cn[j] = idxn[gc * 8 + 8 + j];
      #pragma unroll
      for (int j = 0; j < 8; ++j) xn[j] = xT[(size_t)cn[j] * NB + b];
    }
    const float* wr = wbase + (size_t)gc * 8 * DD;                // uniform rows -> s_load
    #pragma unroll
    for (int u = 0; u < 8; ++u) {
      #pragma unroll
      for (int j = 0; j < 64; ++j)
        acc[j] = fmaf(xv[u], wr[(size_t)u * DD + j], acc[j]);
    }
    #pragma unroll
    for (int j = 0; j < 8; ++j) xv[j] = xn[j];
  }

  // bias + LeakyReLU + partial LN stats
  const float* brow = bias + n * DD + dh * 64;                    // uniform -> s_load
  float sum = 0.f, sum2 = 0.f;
  #pragma unroll
  for (int j = 0; j < 64; ++j) {
    float h = acc[j] + brow[j];
    h = (h >= 0.f) ? h : 0.2f * h;
    acc[j] = h;
    sum += h;
    sum2 += h * h;
  }
  part[dh][lane][0] = sum;
  part[dh][lane][1] = sum2;
  __syncthreads();
  const float ts  = part[0][lane][0] + part[1][lane][0];
  const float ts2 = part[0][lane][1] + part[1][lane][1];
  const float mu  = ts * (1.f / 128.f);
  const float var = ts2 * (1.f / 128.f) - mu * mu;
  const float rs  = rsqrtf(var + 1e-5f);

  // scale + direct contiguous stores (256 B per lane, full-line writes)
  const float* gmp = gamma + dh * 64;                             // uniform -> s_load
  const float* btp = beta  + dh * 64;
  float* orow = out + ((size_t)b * NG + n) * DD + dh * 64;
  #pragma unroll
  for (int j4 = 0; j4 < 16; ++j4) {
    f32x4 v;
    v.x = (acc[4 * j4 + 0] - mu) * rs * gmp[4 * j4 + 0] + btp[4 * j4 + 0];
    v.y = (acc[4 * j4 + 1] - mu) * rs * gmp[4 * j4 + 1] + btp[4 * j4 + 1];
    v.z = (acc[4 * j4 + 2] - mu) * rs * gmp[4 * j4 + 2] + btp[4 * j4 + 2];
    v.w = (acc[4 * j4 + 3] - mu) * rs * gmp[4 * j4 + 3] + btp[4 * j4 + 3];
    *(f32x4*)(orow + 4 * j4) = v;
  }
}

extern "C" void kernel_launch(void* const* d_in, const int* in_sizes, int n_in,
                              void* d_out, int out_size, void* d_ws, size_t ws_size,
                              hipStream_t stream) {
  const float* x     = (const float*)d_in[0];
  const int*   idx   = (const int*)d_in[1];
  const float* W     = (const float*)d_in[2];
  const float* bias  = (const float*)d_in[3];
  const float* gamma = (const float*)d_in[4];
  const float* beta  = (const float*)d_in[5];
  float* out = (float*)d_out;

  float* xT = (float*)d_ws;                      // 8192*512 f32 = 16 MiB

  transpose_x<<<dim3(NFEAT / 64, NB / 64), 256, 0, stream>>>(x, xT);
  lc_f32<<<dim3(NG, NB / 64), 128, 0, stream>>>(xT, W, idx, bias, gamma, beta, out);
}

// Round 4
// 134.759 us; speedup vs baseline: 2.1466x; 2.1466x over previous
//
#include <hip/hip_runtime.h>
#include <stdint.h>

#define NB 512      // batch
#define NFEAT 8192
#define NG 512      // groups
#define GG 64       // gather size / K
#define DD 128      // out features per group

typedef float f32x4 __attribute__((ext_vector_type(4)));

// xT[c][b] = x[b][c], f32, via LDS tile transpose (coalesced both sides)
__global__ __launch_bounds__(256) void transpose_x(const float* __restrict__ x,
                                                   float* __restrict__ xT) {
  __shared__ float t[64][65];
  const int c0 = blockIdx.x * 64;
  const int b0 = blockIdx.y * 64;
  const int tid = threadIdx.x;
  const int col = tid & 63;
  const int rg = tid >> 6;            // 0..3
  #pragma unroll
  for (int r = 0; r < 16; ++r) {
    int row = rg * 16 + r;            // b-local
    t[col][row] = x[(size_t)(b0 + row) * NFEAT + c0 + col];
  }
  __syncthreads();
  #pragma unroll
  for (int r = 0; r < 16; ++r) {
    int crow = rg * 16 + r;           // c-local
    xT[(size_t)(c0 + crow) * NB + b0 + col] = t[crow][col];
  }
}

// One thread = (b, d-half of group n). 128 threads/block = 2 waves (dh 0/1), 64 b rows.
// W rows on the SCALAR path (readfirstlane -> s_load, lgkmcnt queue) overlapping the
// software-pipelined xT gather (VMEM queue). LDS = 1 KB (LN partials only).
__global__ __launch_bounds__(128) void lc_f32(
    const float* __restrict__ xT,
    const float* __restrict__ W,
    const int* __restrict__ idx,
    const float* __restrict__ bias,
    const float* __restrict__ gamma,
    const float* __restrict__ beta,
    float* __restrict__ out) {
  __shared__ float part[2][64][2];    // 1 KiB: LN cross-wave partials

  const int b0 = blockIdx.x * 64;     // b-tile major: consecutive blocks share n
  const int n = blockIdx.y;
  const int tid = threadIdx.x;
  const int lane = tid & 63;
  const int dh = __builtin_amdgcn_readfirstlane(tid >> 6);   // SGPR -> W s_loads
  const int b = b0 + lane;

  const int* idxn = idx + n * GG;
  const float* wbase = W + (size_t)n * (GG * DD) + dh * 64;

  float acc[64];
  #pragma unroll
  for (int j = 0; j < 64; ++j) acc[j] = 0.f;

  // pipeline prologue: chunk 0 gather
  float xv[8];
  {
    int cc[8];
    #pragma unroll
    for (int j = 0; j < 8; ++j) cc[j] = idxn[j];                    // s_load
    #pragma unroll
    for (int j = 0; j < 8; ++j) xv[j] = xT[(size_t)cc[j] * NB + b]; // coalesced VMEM
  }

  for (int gc = 0; gc < 8; ++gc) {
    float xn[8];
    if (gc < 7) {
      int cn[8];
      #pragma unroll
      for (int j = 0; j < 8; ++j) cn[j] = idxn[gc * 8 + 8 + j];
      #pragma unroll
      for (int j = 0; j < 8; ++j) xn[j] = xT[(size_t)cn[j] * NB + b];
    }
    const float* wr = wbase + (size_t)gc * 8 * DD;   // SGPR base -> s_load rows
    #pragma unroll
    for (int u = 0; u < 8; ++u) {
      #pragma unroll
      for (int j = 0; j < 64; ++j)
        acc[j] = fmaf(xv[u], wr[(size_t)u * DD + j], acc[j]);
    }
    #pragma unroll
    for (int j = 0; j < 8; ++j) xv[j] = xn[j];
  }

  // bias + LeakyReLU + partial LN stats
  const float* brow = bias + n * DD + dh * 64;       // SGPR -> s_load
  float sum = 0.f, sum2 = 0.f;
  #pragma unroll
  for (int j = 0; j < 64; ++j) {
    float h = acc[j] + brow[j];
    h = (h >= 0.f) ? h : 0.2f * h;
    acc[j] = h;
    sum += h;
    sum2 += h * h;
  }
  part[dh][lane][0] = sum;
  part[dh][lane][1] = sum2;
  __syncthreads();
  const float ts  = part[0][lane][0] + part[1][lane][0];
  const float ts2 = part[0][lane][1] + part[1][lane][1];
  const float mu  = ts * (1.f / 128.f);
  const float var = ts2 * (1.f / 128.f) - mu * mu;
  const float rs  = rsqrtf(var + 1e-5f);

  // scale + direct contiguous stores (256 B per lane; L2 merges to full lines)
  const float* gmp = gamma + dh * 64;                // SGPR -> s_load
  const float* btp = beta  + dh * 64;
  float* orow = out + ((size_t)b * NG + n) * DD + dh * 64;
  #pragma unroll
  for (int j4 = 0; j4 < 16; ++j4) {
    f32x4 v;
    v.x = (acc[4 * j4 + 0] - mu) * rs * gmp[4 * j4 + 0] + btp[4 * j4 + 0];
    v.y = (acc[4 * j4 + 1] - mu) * rs * gmp[4 * j4 + 1] + btp[4 * j4 + 1];
    v.z = (acc[4 * j4 + 2] - mu) * rs * gmp[4 * j4 + 2] + btp[4 * j4 + 2];
    v.w = (acc[4 * j4 + 3] - mu) * rs * gmp[4 * j4 + 3] + btp[4 * j4 + 3];
    *(f32x4*)(orow + 4 * j4) = v;
  }
}

extern "C" void kernel_launch(void* const* d_in, const int* in_sizes, int n_in,
                              void* d_out, int out_size, void* d_ws, size_t ws_size,
                              hipStream_t stream) {
  const float* x     = (const float*)d_in[0];
  const int*   idx   = (const int*)d_in[1];
  const float* W     = (const float*)d_in[2];
  const float* bias  = (const float*)d_in[3];
  const float* gamma = (const float*)d_in[4];
  const float* beta  = (const float*)d_in[5];
  float* out = (float*)d_out;

  float* xT = (float*)d_ws;                      // 8192*512 f32 = 16 MiB

  transpose_x<<<dim3(NFEAT / 64, NB / 64), 256, 0, stream>>>(x, xT);
  lc_f32<<<dim3(NB / 64, NG), 128, 0, stream>>>(xT, W, idx, bias, gamma, beta, out);
}

// Round 5
// 115.599 us; speedup vs baseline: 2.5024x; 1.1657x over previous
//
#include <hip/hip_runtime.h>
#include <stdint.h>

#define NB 512      // batch
#define NFEAT 8192
#define NG 512      // groups
#define GG 64       // gather size / K
#define DD 128      // out features per group
#define BT 128      // b rows per block

typedef float f32x4 __attribute__((ext_vector_type(4)));

// xT[c][b] = x[b][c], f32, via LDS tile transpose (coalesced both sides)
__global__ __launch_bounds__(256) void transpose_x(const float* __restrict__ x,
                                                   float* __restrict__ xT) {
  __shared__ float t[64][65];
  const int c0 = blockIdx.x * 64;
  const int b0 = blockIdx.y * 64;
  const int tid = threadIdx.x;
  const int col = tid & 63;
  const int rg = tid >> 6;            // 0..3
  #pragma unroll
  for (int r = 0; r < 16; ++r) {
    int row = rg * 16 + r;            // b-local
    t[col][row] = x[(size_t)(b0 + row) * NFEAT + c0 + col];
  }
  __syncthreads();
  #pragma unroll
  for (int r = 0; r < 16; ++r) {
    int crow = rg * 16 + r;           // c-local
    xT[(size_t)(c0 + crow) * NB + b0 + col] = t[crow][col];
  }
}

// Block = (group n, 128 b-rows). 256 threads = 4 waves: (b-group, d-half).
// W_n staged in LDS (32 KB), inner loop reads it via same-address broadcast
// ds_read_b128 (DS pipe) while the gather streams on VMEM — VALU is the only
// contended pipe. Gather software-pipelined 8-deep.
__global__ __launch_bounds__(256) void lc_f32(
    const float* __restrict__ xT,
    const float* __restrict__ W,
    const int* __restrict__ idx,
    const float* __restrict__ bias,
    const float* __restrict__ gamma,
    const float* __restrict__ beta,
    float* __restrict__ out) {
  __shared__ __attribute__((aligned(16))) float wl[GG * DD];  // 32 KiB
  __shared__ float part[2][BT][2];                            // 2 KiB LN partials

  const int n = blockIdx.y;
  const int b0 = blockIdx.x * BT;
  const int tid = threadIdx.x;
  const int lane = tid & 63;
  const int wv = __builtin_amdgcn_readfirstlane(tid >> 6);    // wave id, SGPR
  const int dh = wv & 1;                                      // d-half, SGPR
  const int bg = wv >> 1;                                     // b-group, SGPR
  const int b = b0 + bg * 64 + lane;
  const int bl = bg * 64 + lane;                              // b-local

  // stage W_n -> LDS, coalesced f32x4
  {
    const float* wn = W + (size_t)n * (GG * DD);
    #pragma unroll
    for (int i = 0; i < 8; ++i) {
      int e = (i * 256 + tid) * 4;
      *(f32x4*)&wl[e] = *(const f32x4*)&wn[e];
    }
  }

  const int* idxn = idx + n * GG;                             // SGPR base

  // pipeline prologue: chunk 0 gather (issue before barrier; VMEM overlaps it)
  float xv[8];
  {
    int cc[8];
    #pragma unroll
    for (int j = 0; j < 8; ++j) cc[j] = idxn[j];              // s_load
    #pragma unroll
    for (int j = 0; j < 8; ++j) xv[j] = xT[(size_t)cc[j] * NB + b];
  }

  float acc[64];
  #pragma unroll
  for (int j = 0; j < 64; ++j) acc[j] = 0.f;

  __syncthreads();                                            // W staged

  for (int gc = 0; gc < 8; ++gc) {
    float xn_[8];
    if (gc < 7) {
      int cn[8];
      #pragma unroll
      for (int j = 0; j < 8; ++j) cn[j] = idxn[gc * 8 + 8 + j];
      #pragma unroll
      for (int j = 0; j < 8; ++j) xn_[j] = xT[(size_t)cn[j] * NB + b];
    }
    #pragma unroll
    for (int u = 0; u < 8; ++u) {
      const float xu = xv[u];
      const int base = (gc * 8 + u) * DD + dh * 64;
      #pragma unroll
      for (int j4 = 0; j4 < 16; ++j4) {
        f32x4 wvv = *(const f32x4*)&wl[base + j4 * 4];        // broadcast ds_read_b128
        acc[4 * j4 + 0] = fmaf(xu, wvv.x, acc[4 * j4 + 0]);
        acc[4 * j4 + 1] = fmaf(xu, wvv.y, acc[4 * j4 + 1]);
        acc[4 * j4 + 2] = fmaf(xu, wvv.z, acc[4 * j4 + 2]);
        acc[4 * j4 + 3] = fmaf(xu, wvv.w, acc[4 * j4 + 3]);
      }
    }
    #pragma unroll
    for (int j = 0; j < 8; ++j) xv[j] = xn_[j];
  }

  // bias + LeakyReLU + partial LN stats
  const float* brow = bias + n * DD + dh * 64;                // SGPR -> s_load
  float sum = 0.f, sum2 = 0.f;
  #pragma unroll
  for (int j = 0; j < 64; ++j) {
    float h = acc[j] + brow[j];
    h = (h >= 0.f) ? h : 0.2f * h;
    acc[j] = h;
    sum += h;
    sum2 += h * h;
  }
  part[dh][bl][0] = sum;
  part[dh][bl][1] = sum2;
  __syncthreads();
  const float ts  = part[0][bl][0] + part[1][bl][0];
  const float ts2 = part[0][bl][1] + part[1][bl][1];
  const float mu  = ts * (1.f / 128.f);
  const float var = ts2 * (1.f / 128.f) - mu * mu;
  const float rs  = rsqrtf(var + 1e-5f);

  // scale + direct contiguous stores (256 B per lane)
  const float* gmp = gamma + dh * 64;                         // SGPR -> s_load
  const float* btp = beta  + dh * 64;
  float* orow = out + ((size_t)b * NG + n) * DD + dh * 64;
  #pragma unroll
  for (int j4 = 0; j4 < 16; ++j4) {
    f32x4 v;
    v.x = (acc[4 * j4 + 0] - mu) * rs * gmp[4 * j4 + 0] + btp[4 * j4 + 0];
    v.y = (acc[4 * j4 + 1] - mu) * rs * gmp[4 * j4 + 1] + btp[4 * j4 + 1];
    v.z = (acc[4 * j4 + 2] - mu) * rs * gmp[4 * j4 + 2] + btp[4 * j4 + 2];
    v.w = (acc[4 * j4 + 3] - mu) * rs * gmp[4 * j4 + 3] + btp[4 * j4 + 3];
    *(f32x4*)(orow + 4 * j4) = v;
  }
}

extern "C" void kernel_launch(void* const* d_in, const int* in_sizes, int n_in,
                              void* d_out, int out_size, void* d_ws, size_t ws_size,
                              hipStream_t stream) {
  const float* x     = (const float*)d_in[0];
  const int*   idx   = (const int*)d_in[1];
  const float* W     = (const float*)d_in[2];
  const float* bias  = (const float*)d_in[3];
  const float* gamma = (const float*)d_in[4];
  const float* beta  = (const float*)d_in[5];
  float* out = (float*)d_out;

  float* xT = (float*)d_ws;                      // 8192*512 f32 = 16 MiB

  transpose_x<<<dim3(NFEAT / 64, NB / 64), 256, 0, stream>>>(x, xT);
  lc_f32<<<dim3(NB / BT, NG), 256, 0, stream>>>(xT, W, idx, bias, gamma, beta, out);
}

// Round 6
// 114.957 us; speedup vs baseline: 2.5164x; 1.0056x over previous
//
#include <hip/hip_runtime.h>
#include <stdint.h>

#define NB 512      // batch
#define NFEAT 8192
#define NG 512      // groups
#define GG 64       // gather size / K
#define DD 128      // out features per group
#define BT 128      // b rows per block

typedef float f32x4 __attribute__((ext_vector_type(4)));

// xT[c][b] = x[b][c], f32, via LDS tile transpose (coalesced both sides)
__global__ __launch_bounds__(256) void transpose_x(const float* __restrict__ x,
                                                   float* __restrict__ xT) {
  __shared__ float t[64][65];
  const int c0 = blockIdx.x * 64;
  const int b0 = blockIdx.y * 64;
  const int tid = threadIdx.x;
  const int col = tid & 63;
  const int rg = tid >> 6;            // 0..3
  #pragma unroll
  for (int r = 0; r < 16; ++r) {
    int row = rg * 16 + r;            // b-local
    t[col][row] = x[(size_t)(b0 + row) * NFEAT + c0 + col];
  }
  __syncthreads();
  #pragma unroll
  for (int r = 0; r < 16; ++r) {
    int crow = rg * 16 + r;           // c-local
    xT[(size_t)(c0 + crow) * NB + b0 + col] = t[crow][col];
  }
}

// Block = (group n, 128 b-rows). 256 threads = 4 waves; wave = d-quarter (32 d),
// thread owns b = {lane, lane+64}. W_n in LDS, broadcast ds_read_b128 (only
// lgkmcnt user in the loop). idx held in VGPR lane g -> readlane -> SGPR gather
// base (no SMEM/DS for idx). Gather prefetched 2 chunks (8 g) deep.
__global__ __launch_bounds__(256, 4) void lc_f32(
    const float* __restrict__ xT,
    const float* __restrict__ W,
    const int* __restrict__ idx,
    const float* __restrict__ bias,
    const float* __restrict__ gamma,
    const float* __restrict__ beta,
    float* __restrict__ out) {
  __shared__ __attribute__((aligned(16))) float wl[GG * DD];  // 32 KiB
  __shared__ float part[4][BT][3];                            // 6 KiB (pad 3)

  const int n = blockIdx.y;
  const int b0 = blockIdx.x * BT;
  const int tid = threadIdx.x;
  const int lane = tid & 63;
  const int w = __builtin_amdgcn_readfirstlane(tid >> 6);     // d-quarter, SGPR

  // stage W_n -> LDS, coalesced f32x4
  {
    const float* wn = W + (size_t)n * (GG * DD);
    #pragma unroll
    for (int i = 0; i < 8; ++i) {
      int e = (i * 256 + tid) * 4;
      *(f32x4*)&wl[e] = *(const f32x4*)&wn[e];
    }
  }

  // all 64 idx in one coalesced load: lane g holds idx[n][g]
  const int vidx = idx[n * GG + lane];
  const float* xb = xT + b0 + lane;                           // per-lane base

  // gather pipeline: chunks of 4 g, 2 deep
  float xv[2][4], xn1[2][4], xn2[2][4];
  #pragma unroll
  for (int u = 0; u < 4; ++u) {
    int c = __builtin_amdgcn_readlane(vidx, u);               // SGPR
    xv[0][u] = xb[(size_t)c * NB];
    xv[1][u] = xb[(size_t)c * NB + 64];
  }
  #pragma unroll
  for (int u = 0; u < 4; ++u) {
    int c = __builtin_amdgcn_readlane(vidx, 4 + u);
    xn1[0][u] = xb[(size_t)c * NB];
    xn1[1][u] = xb[(size_t)c * NB + 64];
  }

  float acc[2][32];
  #pragma unroll
  for (int i = 0; i < 2; ++i)
    #pragma unroll
    for (int j = 0; j < 32; ++j) acc[i][j] = 0.f;

  __syncthreads();                                            // W staged

  for (int gc = 0; gc < 16; ++gc) {
    if (gc < 14) {                                            // issue chunk gc+2
      #pragma unroll
      for (int u = 0; u < 4; ++u) {
        int c = __builtin_amdgcn_readlane(vidx, gc * 4 + 8 + u);
        xn2[0][u] = xb[(size_t)c * NB];
        xn2[1][u] = xb[(size_t)c * NB + 64];
      }
    }
    #pragma unroll
    for (int u = 0; u < 4; ++u) {
      const int g = gc * 4 + u;
      const float xu0 = xv[0][u];
      const float xu1 = xv[1][u];
      const int base = g * DD + w * 32;                       // uniform LDS addr
      #pragma unroll
      for (int j4 = 0; j4 < 8; ++j4) {
        f32x4 wf = *(const f32x4*)&wl[base + j4 * 4];         // broadcast b128
        acc[0][4 * j4 + 0] = fmaf(xu0, wf.x, acc[0][4 * j4 + 0]);
        acc[0][4 * j4 + 1] = fmaf(xu0, wf.y, acc[0][4 * j4 + 1]);
        acc[0][4 * j4 + 2] = fmaf(xu0, wf.z, acc[0][4 * j4 + 2]);
        acc[0][4 * j4 + 3] = fmaf(xu0, wf.w, acc[0][4 * j4 + 3]);
        acc[1][4 * j4 + 0] = fmaf(xu1, wf.x, acc[1][4 * j4 + 0]);
        acc[1][4 * j4 + 1] = fmaf(xu1, wf.y, acc[1][4 * j4 + 1]);
        acc[1][4 * j4 + 2] = fmaf(xu1, wf.z, acc[1][4 * j4 + 2]);
        acc[1][4 * j4 + 3] = fmaf(xu1, wf.w, acc[1][4 * j4 + 3]);
      }
    }
    #pragma unroll
    for (int i = 0; i < 2; ++i)
      #pragma unroll
      for (int u = 0; u < 4; ++u) { xv[i][u] = xn1[i][u]; xn1[i][u] = xn2[i][u]; }
  }

  // bias + LeakyReLU + per-quarter LN partials (bias/gamma/beta uniform -> s_load)
  const float* brow = bias + n * DD + w * 32;
  float s0[2] = {0.f, 0.f}, s1[2] = {0.f, 0.f};
  #pragma unroll
  for (int i = 0; i < 2; ++i) {
    #pragma unroll
    for (int j = 0; j < 32; ++j) {
      float h = acc[i][j] + brow[j];
      h = (h >= 0.f) ? h : 0.2f * h;
      acc[i][j] = h;
      s0[i] += h;
      s1[i] += h * h;
    }
  }
  part[w][lane][0] = s0[0];
  part[w][lane][1] = s1[0];
  part[w][lane + 64][0] = s0[1];
  part[w][lane + 64][1] = s1[1];
  __syncthreads();

  const float* gmp = gamma + w * 32;
  const float* btp = beta + w * 32;
  #pragma unroll
  for (int i = 0; i < 2; ++i) {
    const int bl = lane + i * 64;
    float ts = 0.f, ts2 = 0.f;
    #pragma unroll
    for (int q = 0; q < 4; ++q) { ts += part[q][bl][0]; ts2 += part[q][bl][1]; }
    const float mu = ts * (1.f / 128.f);
    const float var = ts2 * (1.f / 128.f) - mu * mu;
    const float rs = rsqrtf(var + 1e-5f);
    float* orow = out + ((size_t)(b0 + bl) * NG + n) * DD + w * 32;
    #pragma unroll
    for (int j4 = 0; j4 < 8; ++j4) {
      f32x4 v;
      v.x = (acc[i][4 * j4 + 0] - mu) * rs * gmp[4 * j4 + 0] + btp[4 * j4 + 0];
      v.y = (acc[i][4 * j4 + 1] - mu) * rs * gmp[4 * j4 + 1] + btp[4 * j4 + 1];
      v.z = (acc[i][4 * j4 + 2] - mu) * rs * gmp[4 * j4 + 2] + btp[4 * j4 + 2];
      v.w = (acc[i][4 * j4 + 3] - mu) * rs * gmp[4 * j4 + 3] + btp[4 * j4 + 3];
      *(f32x4*)(orow + 4 * j4) = v;
    }
  }
}

extern "C" void kernel_launch(void* const* d_in, const int* in_sizes, int n_in,
                              void* d_out, int out_size, void* d_ws, size_t ws_size,
                              hipStream_t stream) {
  const float* x     = (const float*)d_in[0];
  const int*   idx   = (const int*)d_in[1];
  const float* W     = (const float*)d_in[2];
  const float* bias  = (const float*)d_in[3];
  const float* gamma = (const float*)d_in[4];
  const float* beta  = (const float*)d_in[5];
  float* out = (float*)d_out;

  float* xT = (float*)d_ws;                      // 8192*512 f32 = 16 MiB

  transpose_x<<<dim3(NFEAT / 64, NB / 64), 256, 0, stream>>>(x, xT);
  lc_f32<<<dim3(NB / BT, NG), 256, 0, stream>>>(xT, W, idx, bias, gamma, beta, out);
}

// Round 8
// 110.346 us; speedup vs baseline: 2.6215x; 1.0418x over previous
//
#include <hip/hip_runtime.h>
#include <stdint.h>

#define NB 512      // batch
#define NFEAT 8192
#define NG 512      // groups
#define GG 64       // gather size / K
#define DD 128      // out features per group

typedef float f32x4 __attribute__((ext_vector_type(4)));

// xT[c][b] = x[b][c], f32, via LDS tile transpose (coalesced both sides)
__global__ __launch_bounds__(256) void transpose_x(const float* __restrict__ x,
                                                   float* __restrict__ xT) {
  __shared__ float t[64][65];
  const int c0 = blockIdx.x * 64;
  const int b0 = blockIdx.y * 64;
  const int tid = threadIdx.x;
  const int col = tid & 63;
  const int rg = tid >> 6;            // 0..3
  #pragma unroll
  for (int r = 0; r < 16; ++r) {
    int row = rg * 16 + r;            // b-local
    t[col][row] = x[(size_t)(b0 + row) * NFEAT + c0 + col];
  }
  __syncthreads();
  #pragma unroll
  for (int r = 0; r < 16; ++r) {
    int crow = rg * 16 + r;           // c-local
    xT[(size_t)(c0 + crow) * NB + b0 + col] = t[crow][col];
  }
}

struct Stage { f32x4 w0, w1, x; };

// Block = (64 b-rows, group n); 256 threads = 4 waves x 16 b-rows.
// Thread = 4 b x 8 d (d8*4 and 64+d8*4). No LDS, no barriers: W + x stream
// straight from global (L1/L2) with a 3-stage rotating prefetch; LN is
// in-wave via shfl_xor over the 16 d-slices.
__global__ __launch_bounds__(256) void lc_f32(
    const float* __restrict__ xT,
    const float* __restrict__ W,
    const int* __restrict__ idx,
    const float* __restrict__ bias,
    const float* __restrict__ gamma,
    const float* __restrict__ beta,
    float* __restrict__ out) {
  const int n = blockIdx.y;
  const int b0 = blockIdx.x * 64;
  const int tid = threadIdx.x;
  const int lane = tid & 63;
  const int w = __builtin_amdgcn_readfirstlane(tid >> 6);  // wave id, SGPR
  const int bo = lane >> 4;                                // b-quad 0..3
  const int d8 = lane & 15;                                // d-slice 0..15
  const int dlo = d8 * 4;                                  // d chunk 1
  const int dhi = 64 + d8 * 4;                             // d chunk 2
  const int bb = b0 + w * 16 + bo * 4;                     // thread's first b-row
  const int bbase = w * 16 + bo * 4;                       // b-offset within block tile

  const float* wn = W + (size_t)n * (GG * DD);             // SGPR base
  const float* xtb = xT + b0;                              // block x base
  const int vidx = idx[n * GG + lane];                     // lane g holds idx[n][g]

  float acc[4][2][4];
  #pragma unroll
  for (int r = 0; r < 4; ++r)
    #pragma unroll
    for (int h = 0; h < 2; ++h)
      #pragma unroll
      for (int j = 0; j < 4; ++j) acc[r][h][j] = 0.f;

  auto stage_load = [&](Stage& S, int gg) {
    int c_ = __builtin_amdgcn_readlane(vidx, gg);          // SGPR idx
    const float* xr_ = xtb + (size_t)c_ * NB;
    S.x  = *(const f32x4*)(xr_ + bbase);
    const float* wr_ = wn + (size_t)gg * DD;
    S.w0 = *(const f32x4*)(wr_ + dlo);
    S.w1 = *(const f32x4*)(wr_ + dhi);
  };

  auto compute = [&](const Stage& S) {
    #pragma unroll
    for (int r = 0; r < 4; ++r) {
      const float xv_ = S.x[r];
      #pragma unroll
      for (int j = 0; j < 4; ++j) {
        acc[r][0][j] = fmaf(xv_, S.w0[j], acc[r][0][j]);
        acc[r][1][j] = fmaf(xv_, S.w1[j], acc[r][1][j]);
      }
    }
  };

  Stage sA, sB, sC;
  stage_load(sA, 0);
  stage_load(sB, 1);
  stage_load(sC, 2);

  #pragma unroll
  for (int k = 0; k < 21; ++k) {
    const int g = 3 * k;
    compute(sA); stage_load(sA, (g + 3) & 63);
    compute(sB); stage_load(sB, (g + 4) & 63);
    compute(sC); stage_load(sC, (g + 5) & 63);
  }
  compute(sA);                        // g = 63 (loaded at k=20)

  // bias + LeakyReLU + in-wave LN over the 16 d-slices
  const f32x4 bv0 = *(const f32x4*)(bias + n * DD + dlo);
  const f32x4 bv1 = *(const f32x4*)(bias + n * DD + dhi);
  const f32x4 gv0 = *(const f32x4*)(gamma + dlo);
  const f32x4 gv1 = *(const f32x4*)(gamma + dhi);
  const f32x4 tv0 = *(const f32x4*)(beta + dlo);
  const f32x4 tv1 = *(const f32x4*)(beta + dhi);

  #pragma unroll
  for (int r = 0; r < 4; ++r) {
    float s = 0.f, s2 = 0.f;
    #pragma unroll
    for (int j = 0; j < 4; ++j) {
      float h0 = acc[r][0][j] + bv0[j];
      h0 = (h0 >= 0.f) ? h0 : 0.2f * h0;
      float h1 = acc[r][1][j] + bv1[j];
      h1 = (h1 >= 0.f) ? h1 : 0.2f * h1;
      acc[r][0][j] = h0; acc[r][1][j] = h1;
      s += h0 + h1;
      s2 += h0 * h0 + h1 * h1;
    }
    s  += __shfl_xor(s, 1);  s  += __shfl_xor(s, 2);
    s  += __shfl_xor(s, 4);  s  += __shfl_xor(s, 8);
    s2 += __shfl_xor(s2, 1); s2 += __shfl_xor(s2, 2);
    s2 += __shfl_xor(s2, 4); s2 += __shfl_xor(s2, 8);
    const float mu = s * (1.f / 128.f);
    const float var = s2 * (1.f / 128.f) - mu * mu;
    const float rs = rsqrtf(var + 1e-5f);

    float* orow = out + ((size_t)(bb + r) * NG + n) * DD;
    f32x4 v0, v1;
    #pragma unroll
    for (int j = 0; j < 4; ++j) {
      v0[j] = (acc[r][0][j] - mu) * rs * gv0[j] + tv0[j];
      v1[j] = (acc[r][1][j] - mu) * rs * gv1[j] + tv1[j];
    }
    *(f32x4*)(orow + dlo) = v0;
    *(f32x4*)(orow + dhi) = v1;
  }
}

extern "C" void kernel_launch(void* const* d_in, const int* in_sizes, int n_in,
                              void* d_out, int out_size, void* d_ws, size_t ws_size,
                              hipStream_t stream) {
  const float* x     = (const float*)d_in[0];
  const int*   idx   = (const int*)d_in[1];
  const float* W     = (const float*)d_in[2];
  const float* bias  = (const float*)d_in[3];
  const float* gamma = (const float*)d_in[4];
  const float* beta  = (const float*)d_in[5];
  float* out = (float*)d_out;

  float* xT = (float*)d_ws;                      // 8192*512 f32 = 16 MiB

  transpose_x<<<dim3(NFEAT / 64, NB / 64), 256, 0, stream>>>(x, xT);
  lc_f32<<<dim3(NB / 64, NG), 256, 0, stream>>>(xT, W, idx, bias, gamma, beta, out);
}

// Round 9
// 91.182 us; speedup vs baseline: 3.1725x; 1.2102x over previous
//
#include <hip/hip_runtime.h>
#include <stdint.h>

#define NB 512      // batch
#define NFEAT 8192
#define NG 512      // groups
#define GG 64       // gather size / K
#define DD 128      // out features per group

typedef float f32x4 __attribute__((ext_vector_type(4)));

// xT[c][b] = x[b][c], f32, via LDS tile transpose (coalesced both sides)
__global__ __launch_bounds__(256) void transpose_x(const float* __restrict__ x,
                                                   float* __restrict__ xT) {
  __shared__ float t[64][65];
  const int c0 = blockIdx.x * 64;
  const int b0 = blockIdx.y * 64;
  const int tid = threadIdx.x;
  const int col = tid & 63;
  const int rg = tid >> 6;            // 0..3
  #pragma unroll
  for (int r = 0; r < 16; ++r) {
    int row = rg * 16 + r;            // b-local
    t[col][row] = x[(size_t)(b0 + row) * NFEAT + c0 + col];
  }
  __syncthreads();
  #pragma unroll
  for (int r = 0; r < 16; ++r) {
    int crow = rg * 16 + r;           // c-local
    xT[(size_t)(c0 + crow) * NB + b0 + col] = t[crow][col];
  }
}

struct Stage { f32x4 x0, x1, w0, w1; };

// Block = (128 b-rows, group n); 256 threads = 4 waves x 32 b-rows.
// Thread = 8 b x 8 d. No LDS/barriers; W + x stream from global with a
// depth-3 rotating prefetch (64 FMA per 4 VMEM). Out stores are
// NON-TEMPORAL so the 128 MB write stream doesn't evict xT/W from L3.
__global__ __launch_bounds__(256) void lc_f32(
    const float* __restrict__ xT,
    const float* __restrict__ W,
    const int* __restrict__ idx,
    const float* __restrict__ bias,
    const float* __restrict__ gamma,
    const float* __restrict__ beta,
    float* __restrict__ out) {
  const int n = blockIdx.y;
  const int b0 = blockIdx.x * 128;
  const int tid = threadIdx.x;
  const int lane = tid & 63;
  const int w = __builtin_amdgcn_readfirstlane(tid >> 6);  // wave id, SGPR
  const int bo = lane >> 4;                                // b-octet 0..3
  const int d8 = lane & 15;                                // d-slice 0..15
  const int dlo = d8 * 4;
  const int dhi = 64 + d8 * 4;
  const int bloc = w * 32 + bo * 8;                        // first b in block tile

  const float* wn = W + (size_t)n * (GG * DD);             // SGPR base
  const float* xtb = xT + b0 + bloc;                       // + c*NB per g
  const int vidx = idx[n * GG + lane];                     // lane g holds idx[n][g]

  float acc[8][8];                                         // [b-row][d]
  #pragma unroll
  for (int r = 0; r < 8; ++r)
    #pragma unroll
    for (int j = 0; j < 8; ++j) acc[r][j] = 0.f;

  auto stage_load = [&](Stage& S, int gg) {
    int c_ = __builtin_amdgcn_readlane(vidx, gg);          // SGPR idx
    const float* xr_ = xtb + (size_t)c_ * NB;
    S.x0 = *(const f32x4*)(xr_);
    S.x1 = *(const f32x4*)(xr_ + 4);
    const float* wr_ = wn + (size_t)gg * DD;
    S.w0 = *(const f32x4*)(wr_ + dlo);
    S.w1 = *(const f32x4*)(wr_ + dhi);
  };

  auto compute = [&](const Stage& S) {
    #pragma unroll
    for (int r = 0; r < 4; ++r) {
      const float xa = S.x0[r];
      const float xb = S.x1[r];
      #pragma unroll
      for (int j = 0; j < 4; ++j) {
        acc[r][j]         = fmaf(xa, S.w0[j], acc[r][j]);
        acc[r][4 + j]     = fmaf(xa, S.w1[j], acc[r][4 + j]);
        acc[4 + r][j]     = fmaf(xb, S.w0[j], acc[4 + r][j]);
        acc[4 + r][4 + j] = fmaf(xb, S.w1[j], acc[4 + r][4 + j]);
      }
    }
  };

  Stage sA, sB, sC;
  stage_load(sA, 0);
  stage_load(sB, 1);
  stage_load(sC, 2);

  #pragma unroll
  for (int k = 0; k < 21; ++k) {
    const int g = 3 * k;
    compute(sA); stage_load(sA, (g + 3) & 63);
    compute(sB); stage_load(sB, (g + 4) & 63);
    compute(sC); stage_load(sC, (g + 5) & 63);
  }
  compute(sA);                        // g = 63 (loaded at k=20)

  // bias + LeakyReLU + in-wave LN over the 16 d-slices
  const f32x4 bv0 = *(const f32x4*)(bias + n * DD + dlo);
  const f32x4 bv1 = *(const f32x4*)(bias + n * DD + dhi);
  const f32x4 gv0 = *(const f32x4*)(gamma + dlo);
  const f32x4 gv1 = *(const f32x4*)(gamma + dhi);
  const f32x4 tv0 = *(const f32x4*)(beta + dlo);
  const f32x4 tv1 = *(const f32x4*)(beta + dhi);

  #pragma unroll
  for (int r = 0; r < 8; ++r) {
    float s = 0.f, s2 = 0.f;
    #pragma unroll
    for (int j = 0; j < 4; ++j) {
      float h0 = acc[r][j] + bv0[j];
      h0 = (h0 >= 0.f) ? h0 : 0.2f * h0;
      float h1 = acc[r][4 + j] + bv1[j];
      h1 = (h1 >= 0.f) ? h1 : 0.2f * h1;
      acc[r][j] = h0; acc[r][4 + j] = h1;
      s += h0 + h1;
      s2 += h0 * h0 + h1 * h1;
    }
    s  += __shfl_xor(s, 1);  s  += __shfl_xor(s, 2);
    s  += __shfl_xor(s, 4);  s  += __shfl_xor(s, 8);
    s2 += __shfl_xor(s2, 1); s2 += __shfl_xor(s2, 2);
    s2 += __shfl_xor(s2, 4); s2 += __shfl_xor(s2, 8);
    const float mu = s * (1.f / 128.f);
    const float var = s2 * (1.f / 128.f) - mu * mu;
    const float rs = rsqrtf(var + 1e-5f);

    float* orow = out + ((size_t)(b0 + bloc + r) * NG + n) * DD;
    f32x4 v0, v1;
    #pragma unroll
    for (int j = 0; j < 4; ++j) {
      v0[j] = (acc[r][j] - mu) * rs * gv0[j] + tv0[j];
      v1[j] = (acc[r][4 + j] - mu) * rs * gv1[j] + tv1[j];
    }
    __builtin_nontemporal_store(v0, (f32x4*)(orow + dlo));
    __builtin_nontemporal_store(v1, (f32x4*)(orow + dhi));
  }
}

extern "C" void kernel_launch(void* const* d_in, const int* in_sizes, int n_in,
                              void* d_out, int out_size, void* d_ws, size_t ws_size,
                              hipStream_t stream) {
  const float* x     = (const float*)d_in[0];
  const int*   idx   = (const int*)d_in[1];
  const float* W     = (const float*)d_in[2];
  const float* bias  = (const float*)d_in[3];
  const float* gamma = (const float*)d_in[4];
  const float* beta  = (const float*)d_in[5];
  float* out = (float*)d_out;

  float* xT = (float*)d_ws;                      // 8192*512 f32 = 16 MiB

  transpose_x<<<dim3(NFEAT / 64, NB / 64), 256, 0, stream>>>(x, xT);
  lc_f32<<<dim3(NB / 128, NG), 256, 0, stream>>>(xT, W, idx, bias, gamma, beta, out);
}

// Round 12
// 65.888 us; speedup vs baseline: 4.3904x; 1.3839x over previous
//
#include <hip/hip_runtime.h>
#include <stdint.h>

#define NB 512      // batch
#define NFEAT 8192
#define NG 512      // groups
#define GG 64       // gather size / K
#define DD 128      // out features per group

typedef short bf16x8 __attribute__((ext_vector_type(8)));
typedef float f32x4 __attribute__((ext_vector_type(4)));
typedef unsigned int u32x4 __attribute__((ext_vector_type(4)));
typedef unsigned short u16;

__device__ __forceinline__ u16 f2bf(float f) {
  unsigned u = __builtin_bit_cast(unsigned, f);
  u += 0x7FFFu + ((u >> 16) & 1u);   // RNE
  return (u16)(u >> 16);
}

// xTb[c][b] = bf16(x[b][c]) — verified f32 transpose structure + cast on write
__global__ __launch_bounds__(256) void prep_x(const float* __restrict__ x,
                                              u16* __restrict__ xTb) {
  __shared__ float t[64][65];
  const int c0 = blockIdx.x * 64;
  const int b0 = blockIdx.y * 64;
  const int tid = threadIdx.x;
  const int col = tid & 63;
  const int rg = tid >> 6;
  #pragma unroll
  for (int r = 0; r < 16; ++r) {
    int row = rg * 16 + r;            // b-local
    t[col][row] = x[(size_t)(b0 + row) * NFEAT + c0 + col];
  }
  __syncthreads();
  #pragma unroll
  for (int r = 0; r < 16; ++r) {
    int crow = rg * 16 + r;           // c-local
    xTb[(size_t)(c0 + crow) * NB + b0 + col] = f2bf(t[crow][col]);
  }
}

// Wt[n][d][g] = bf16(W[n][g][d]) via LDS tile (one block per n)
__global__ __launch_bounds__(256) void prep_wt(const float* __restrict__ W,
                                               u16* __restrict__ Wt) {
  __shared__ u16 tl[DD][GG + 8];
  const int n = blockIdx.x;
  const int tid = threadIdx.x;
  const float* wn = W + (size_t)n * (GG * DD);
  #pragma unroll
  for (int i = 0; i < 32; ++i) {
    int e = i * 256 + tid;            // coalesced read
    int g = e >> 7, d = e & 127;
    tl[d][g] = f2bf(wn[e]);
  }
  __syncthreads();
  u16* dst = Wt + (size_t)n * (DD * GG);
  const int d = tid >> 1, gh = (tid & 1) * 32;
  #pragma unroll
  for (int k = 0; k < 32; ++k)
    dst[d * GG + gh + k] = tl[d][gh + k];
}

// Block = (64 b, group n); 4 waves, wave = 16 b x 128 d. No LDS.
// A-frag: per-lane u16 gathers from xTb; B-frag: bf16x8 loads from Wt (L2).
// A and B use the IDENTICAL slot->g map g = ks*32 + q*8 + j (shared
// k-permutation cancels; m97-verified pattern). C/D map (m89): row=(l>>4)*4+r,
// col=l&15. Epilogue: full LN with mean subtraction (round-10/11 bug fixed).
__global__ __launch_bounds__(256) void lc_mfma(
    const u16* __restrict__ xTb,
    const u16* __restrict__ Wt,
    const int* __restrict__ idx,
    const float* __restrict__ bias,
    const float* __restrict__ gamma,
    const float* __restrict__ beta,
    float* __restrict__ out) {
  const int n = blockIdx.y;
  const int b0 = blockIdx.x * 64;
  const int tid = threadIdx.x;
  const int lane = tid & 63;
  const int w = tid >> 6;            // wave's 16-b slice
  const int q = lane >> 4;
  const int lm = lane & 15;
  const int bb = b0 + w * 16;
  const int arow = bb + lm;          // A row

  const int* idxn = idx + n * GG;

  // per-lane gather offsets for g = ks*32 + q*8 + j
  int cof[16];
  #pragma unroll
  for (int ks = 0; ks < 2; ++ks)
    #pragma unroll
    for (int j = 0; j < 8; ++j)
      cof[ks * 8 + j] = idxn[ks * 32 + q * 8 + j] * NB;

  // A fragments (row = arow), element e holds g = ks*32 + q*8 + e
  bf16x8 afr[2];
  #pragma unroll
  for (int ks = 0; ks < 2; ++ks) {
    unsigned p[4];
    #pragma unroll
    for (int r = 0; r < 4; ++r) {
      unsigned t0 = xTb[cof[ks * 8 + 2 * r]     + arow];
      unsigned t1 = xTb[cof[ks * 8 + 2 * r + 1] + arow];
      p[r] = t0 | (t1 << 16);
    }
    u32x4 a4; a4.x = p[0]; a4.y = p[1]; a4.z = p[2]; a4.w = p[3];
    afr[ks] = __builtin_bit_cast(bf16x8, a4);
  }

  // B fragments + MFMA: col d = ni*16+lm, contiguous g-run in Wt[n][d][*]
  const u16* wtn = Wt + (size_t)n * (DD * GG);
  f32x4 acc[8];
  #pragma unroll
  for (int ni = 0; ni < 8; ++ni) acc[ni] = f32x4{0.f, 0.f, 0.f, 0.f};

  #pragma unroll
  for (int ks = 0; ks < 2; ++ks) {
    #pragma unroll
    for (int ni = 0; ni < 8; ++ni) {
      const int d = ni * 16 + lm;
      bf16x8 bfr = *(const bf16x8*)(wtn + d * GG + ks * 32 + q * 8);
      acc[ni] = __builtin_amdgcn_mfma_f32_16x16x32_bf16(afr[ks], bfr, acc[ni], 0, 0, 0);
    }
  }

  // epilogue: +bias, LeakyReLU, LN over d (row q*4+r lives in 16 lm-lanes x 8 regs)
  float bv[8], gv[8], tv[8];
  #pragma unroll
  for (int ni = 0; ni < 8; ++ni) {
    const int d = ni * 16 + lm;
    bv[ni] = bias[n * DD + d];
    gv[ni] = gamma[d];
    tv[ni] = beta[d];
  }
  #pragma unroll
  for (int r = 0; r < 4; ++r) {
    float h[8];
    float s = 0.f, s2 = 0.f;
    #pragma unroll
    for (int ni = 0; ni < 8; ++ni) {
      float v = acc[ni][r] + bv[ni];
      v = (v >= 0.f) ? v : 0.2f * v;
      h[ni] = v;
      s += v;
      s2 += v * v;
    }
    s  += __shfl_xor(s, 1);  s  += __shfl_xor(s, 2);
    s  += __shfl_xor(s, 4);  s  += __shfl_xor(s, 8);
    s2 += __shfl_xor(s2, 1); s2 += __shfl_xor(s2, 2);
    s2 += __shfl_xor(s2, 4); s2 += __shfl_xor(s2, 8);
    const float mu = s * (1.f / 128.f);
    const float var = s2 * (1.f / 128.f) - mu * mu;
    const float rs = rsqrtf(var + 1e-5f);

    const int brow = bb + q * 4 + r;
    float* ob = out + ((size_t)brow * NG + n) * DD + lm;
    #pragma unroll
    for (int ni = 0; ni < 8; ++ni)
      __builtin_nontemporal_store((h[ni] - mu) * rs * gv[ni] + tv[ni], ob + ni * 16);
  }
}

extern "C" void kernel_launch(void* const* d_in, const int* in_sizes, int n_in,
                              void* d_out, int out_size, void* d_ws, size_t ws_size,
                              hipStream_t stream) {
  const float* x     = (const float*)d_in[0];
  const int*   idx   = (const int*)d_in[1];
  const float* W     = (const float*)d_in[2];
  const float* bias  = (const float*)d_in[3];
  const float* gamma = (const float*)d_in[4];
  const float* beta  = (const float*)d_in[5];
  float* out = (float*)d_out;

  u16* xTb = (u16*)d_ws;                           // 8192*512 bf16 = 8 MiB
  u16* Wt  = xTb + (size_t)NFEAT * NB;             // 512*128*64 bf16 = 8 MiB

  prep_x <<<dim3(NFEAT / 64, NB / 64), 256, 0, stream>>>(x, xTb);
  prep_wt<<<NG, 256, 0, stream>>>(W, Wt);
  lc_mfma<<<dim3(NB / 64, NG), 256, 0, stream>>>(xTb, Wt, idx, bias, gamma, beta, out);
}

// Round 13
// 59.739 us; speedup vs baseline: 4.8423x; 1.1029x over previous
//
#include <hip/hip_runtime.h>
#include <stdint.h>

#define NB 512      // batch
#define NFEAT 8192
#define NG 512      // groups
#define GG 64       // gather size / K
#define DD 128      // out features per group

typedef short bf16x8 __attribute__((ext_vector_type(8)));
typedef float f32x4 __attribute__((ext_vector_type(4)));
typedef unsigned int u32x4 __attribute__((ext_vector_type(4)));
typedef unsigned short u16;

__device__ __forceinline__ u16 f2bf(float f) {
  unsigned u = __builtin_bit_cast(unsigned, f);
  u += 0x7FFFu + ((u >> 16) & 1u);   // RNE
  return (u16)(u >> 16);
}

// Fused prep: blocks [0,1024) do xTb[c][b] = bf16(x[b][c]);
// blocks [1024,1536) do Wt[n][d][g] = bf16(W[n][g][d]).
__global__ __launch_bounds__(256) void prep_fused(const float* __restrict__ x,
                                                  u16* __restrict__ xTb,
                                                  const float* __restrict__ W,
                                                  u16* __restrict__ Wt) {
  __shared__ __attribute__((aligned(16))) char lds[18432];
  const int bid = blockIdx.x;
  const int tid = threadIdx.x;
  if (bid < 1024) {
    float (*t)[65] = (float (*)[65])lds;           // 64 x 65 f32 = 16.6 KB
    const int c0 = (bid & 127) * 64;
    const int b0 = (bid >> 7) * 64;
    const int col = tid & 63;
    const int rg = tid >> 6;
    #pragma unroll
    for (int r = 0; r < 16; ++r) {
      int row = rg * 16 + r;          // b-local
      t[col][row] = x[(size_t)(b0 + row) * NFEAT + c0 + col];
    }
    __syncthreads();
    #pragma unroll
    for (int r = 0; r < 16; ++r) {
      int crow = rg * 16 + r;         // c-local
      xTb[(size_t)(c0 + crow) * NB + b0 + col] = f2bf(t[crow][col]);
    }
  } else {
    u16 (*tl)[GG + 8] = (u16 (*)[GG + 8])lds;      // 128 x 72 u16 = 18.4 KB
    const int n = bid - 1024;
    const float* wn = W + (size_t)n * (GG * DD);
    #pragma unroll
    for (int i = 0; i < 32; ++i) {
      int e = i * 256 + tid;          // coalesced read
      int g = e >> 7, d = e & 127;
      tl[d][g] = f2bf(wn[e]);
    }
    __syncthreads();
    u16* dst = Wt + (size_t)n * (DD * GG);
    const int d = tid >> 1, gh = (tid & 1) * 32;
    #pragma unroll
    for (int k = 0; k < 32; ++k)
      dst[d * GG + gh + k] = tl[d][gh + k];
  }
}

// Block = (128 b, group n); 4 waves, wave = 32 b (2 m-tiles) x 128 d. No LDS.
// A-frag: per-lane u16 gathers from xTb; B-frag: bf16x8 from Wt (L2), loaded
// once and reused by both m-tiles. Shared slot->g map g = ks*32 + q*8 + j;
// C/D map (m89): row=(l>>4)*4+r, col=l&15. LN epilogue with mean subtraction.
__global__ __launch_bounds__(256) void lc_mfma(
    const u16* __restrict__ xTb,
    const u16* __restrict__ Wt,
    const int* __restrict__ idx,
    const float* __restrict__ bias,
    const float* __restrict__ gamma,
    const float* __restrict__ beta,
    float* __restrict__ out) {
  const int n = blockIdx.y;
  const int b0 = blockIdx.x * 128;
  const int tid = threadIdx.x;
  const int lane = tid & 63;
  const int w = tid >> 6;            // wave's 32-b slice
  const int q = lane >> 4;
  const int lm = lane & 15;
  const int bb = b0 + w * 32;

  const int* idxn = idx + n * GG;

  // per-lane gather offsets for g = ks*32 + q*8 + j
  int cof[16];
  #pragma unroll
  for (int ks = 0; ks < 2; ++ks)
    #pragma unroll
    for (int j = 0; j < 8; ++j)
      cof[ks * 8 + j] = idxn[ks * 32 + q * 8 + j] * NB;

  // A fragments for both m-tiles (rows bb+mi*16+lm)
  bf16x8 afr[2][2];                  // [ks][mi]
  #pragma unroll
  for (int mi = 0; mi < 2; ++mi) {
    const int arow = bb + mi * 16 + lm;
    #pragma unroll
    for (int ks = 0; ks < 2; ++ks) {
      unsigned p[4];
      #pragma unroll
      for (int r = 0; r < 4; ++r) {
        unsigned t0 = xTb[cof[ks * 8 + 2 * r]     + arow];
        unsigned t1 = xTb[cof[ks * 8 + 2 * r + 1] + arow];
        p[r] = t0 | (t1 << 16);
      }
      u32x4 a4; a4.x = p[0]; a4.y = p[1]; a4.z = p[2]; a4.w = p[3];
      afr[ks][mi] = __builtin_bit_cast(bf16x8, a4);
    }
  }

  // B fragments + MFMA: each B-frag feeds both m-tiles
  const u16* wtn = Wt + (size_t)n * (DD * GG);
  f32x4 acc[2][8];                   // [mi][ni]
  #pragma unroll
  for (int mi = 0; mi < 2; ++mi)
    #pragma unroll
    for (int ni = 0; ni < 8; ++ni) acc[mi][ni] = f32x4{0.f, 0.f, 0.f, 0.f};

  #pragma unroll
  for (int ks = 0; ks < 2; ++ks) {
    #pragma unroll
    for (int ni = 0; ni < 8; ++ni) {
      const int d = ni * 16 + lm;
      bf16x8 bfr = *(const bf16x8*)(wtn + d * GG + ks * 32 + q * 8);
      acc[0][ni] = __builtin_amdgcn_mfma_f32_16x16x32_bf16(afr[ks][0], bfr, acc[0][ni], 0, 0, 0);
      acc[1][ni] = __builtin_amdgcn_mfma_f32_16x16x32_bf16(afr[ks][1], bfr, acc[1][ni], 0, 0, 0);
    }
  }

  // epilogue: +bias, LeakyReLU, LN over d (row mi*16+q*4+r in 16 lm-lanes x 8 regs)
  float bv[8], gv[8], tv[8];
  #pragma unroll
  for (int ni = 0; ni < 8; ++ni) {
    const int d = ni * 16 + lm;
    bv[ni] = bias[n * DD + d];
    gv[ni] = gamma[d];
    tv[ni] = beta[d];
  }
  #pragma unroll
  for (int mi = 0; mi < 2; ++mi) {
    #pragma unroll
    for (int r = 0; r < 4; ++r) {
      float h[8];
      float s = 0.f, s2 = 0.f;
      #pragma unroll
      for (int ni = 0; ni < 8; ++ni) {
        float v = acc[mi][ni][r] + bv[ni];
        v = (v >= 0.f) ? v : 0.2f * v;
        h[ni] = v;
        s += v;
        s2 += v * v;
      }
      s  += __shfl_xor(s, 1);  s  += __shfl_xor(s, 2);
      s  += __shfl_xor(s, 4);  s  += __shfl_xor(s, 8);
      s2 += __shfl_xor(s2, 1); s2 += __shfl_xor(s2, 2);
      s2 += __shfl_xor(s2, 4); s2 += __shfl_xor(s2, 8);
      const float mu = s * (1.f / 128.f);
      const float var = s2 * (1.f / 128.f) - mu * mu;
      const float rs = rsqrtf(var + 1e-5f);

      const int brow = bb + mi * 16 + q * 4 + r;
      float* ob = out + ((size_t)brow * NG + n) * DD + lm;
      #pragma unroll
      for (int ni = 0; ni < 8; ++ni)
        __builtin_nontemporal_store((h[ni] - mu) * rs * gv[ni] + tv[ni], ob + ni * 16);
    }
  }
}

extern "C" void kernel_launch(void* const* d_in, const int* in_sizes, int n_in,
                              void* d_out, int out_size, void* d_ws, size_t ws_size,
                              hipStream_t stream) {
  const float* x     = (const float*)d_in[0];
  const int*   idx   = (const int*)d_in[1];
  const float* W     = (const float*)d_in[2];
  const float* bias  = (const float*)d_in[3];
  const float* gamma = (const float*)d_in[4];
  const float* beta  = (const float*)d_in[5];
  float* out = (float*)d_out;

  u16* xTb = (u16*)d_ws;                           // 8192*512 bf16 = 8 MiB
  u16* Wt  = xTb + (size_t)NFEAT * NB;             // 512*128*64 bf16 = 8 MiB

  prep_fused<<<1536, 256, 0, stream>>>(x, xTb, W, Wt);
  lc_mfma<<<dim3(NB / 128, NG), 256, 0, stream>>>(xTb, Wt, idx, bias, gamma, beta, out);
}

// Round 14
// 55.843 us; speedup vs baseline: 5.1801x; 1.0698x over previous
//
#include <hip/hip_runtime.h>
#include <stdint.h>

#define NB 512      // batch
#define NFEAT 8192
#define NG 512      // groups
#define GG 64       // gather size / K
#define DD 128      // out features per group

typedef short bf16x8 __attribute__((ext_vector_type(8)));
typedef float f32x4 __attribute__((ext_vector_type(4)));
typedef unsigned int u32x4 __attribute__((ext_vector_type(4)));
typedef unsigned short u16;

__device__ __forceinline__ u16 f2bf(float f) {
  unsigned u = __builtin_bit_cast(unsigned, f);
  u += 0x7FFFu + ((u >> 16) & 1u);   // RNE
  return (u16)(u >> 16);
}

// Fused prep: blocks [0,1024) do xTb[c][b] = bf16(x[b][c]);
// blocks [1024,1536) do Wt[n][d][g] = bf16(W[n][g][d]).
__global__ __launch_bounds__(256) void prep_fused(const float* __restrict__ x,
                                                  u16* __restrict__ xTb,
                                                  const float* __restrict__ W,
                                                  u16* __restrict__ Wt) {
  __shared__ __attribute__((aligned(16))) char lds[18432];
  const int bid = blockIdx.x;
  const int tid = threadIdx.x;
  if (bid < 1024) {
    float (*t)[65] = (float (*)[65])lds;           // 64 x 65 f32 = 16.6 KB
    const int c0 = (bid & 127) * 64;
    const int b0 = (bid >> 7) * 64;
    const int col = tid & 63;
    const int rg = tid >> 6;
    #pragma unroll
    for (int r = 0; r < 16; ++r) {
      int row = rg * 16 + r;          // b-local
      t[col][row] = x[(size_t)(b0 + row) * NFEAT + c0 + col];
    }
    __syncthreads();
    // packed u32 stores: 2 b per lane -> 256 B per instruction
    const int sc = tid & 31;          // b-pair
    const int srg = tid >> 5;         // 0..7
    #pragma unroll
    for (int r = 0; r < 8; ++r) {
      int crow = srg * 8 + r;         // c-local
      unsigned px = (unsigned)f2bf(t[crow][2 * sc]) |
                    ((unsigned)f2bf(t[crow][2 * sc + 1]) << 16);
      *(unsigned*)(xTb + (size_t)(c0 + crow) * NB + b0 + 2 * sc) = px;
    }
  } else {
    u16 (*tl)[GG + 8] = (u16 (*)[GG + 8])lds;      // 128 x 72 u16 = 18.4 KB
    const int n = bid - 1024;
    const float* wn = W + (size_t)n * (GG * DD);
    #pragma unroll
    for (int i = 0; i < 32; ++i) {
      int e = i * 256 + tid;          // coalesced read
      int g = e >> 7, d = e & 127;
      tl[d][g] = f2bf(wn[e]);
    }
    __syncthreads();
    u16* dst = Wt + (size_t)n * (DD * GG);
    const int d = tid >> 1, gh = (tid & 1) * 32;
    const u16* src = &tl[d][gh];
    u32x4 v0 = *(const u32x4*)(src);
    u32x4 v1 = *(const u32x4*)(src + 8);
    u32x4 v2 = *(const u32x4*)(src + 16);
    u32x4 v3 = *(const u32x4*)(src + 24);
    u32x4* dp = (u32x4*)(dst + d * GG + gh);
    dp[0] = v0; dp[1] = v1; dp[2] = v2; dp[3] = v3;
  }
}

// Block = (128 b, group n), XCD-swizzled 1D grid: all 4 b-tiles of group n
// land on XCD n%8 so Wt[n]/idx[n] are L2-local. 4 waves, wave = 32 b
// (2 m-tiles) x 128 d. No LDS. A-frag: per-lane u16 gathers from xTb;
// B-frag: bf16x8 from Wt, reused by both m-tiles. Shared slot->g map
// g = ks*32 + q*8 + j; C/D map (m89): row=(l>>4)*4+r, col=l&15.
__global__ __launch_bounds__(256) void lc_mfma(
    const u16* __restrict__ xTb,
    const u16* __restrict__ Wt,
    const int* __restrict__ idx,
    const float* __restrict__ bias,
    const float* __restrict__ gamma,
    const float* __restrict__ beta,
    float* __restrict__ out) {
  const int lin = blockIdx.x;
  const int xcd = lin & 7;
  const int slot = lin >> 3;
  const int n = (slot & 63) * 8 + xcd;   // n % 8 == xcd
  const int b0 = (slot >> 6) * 128;
  const int tid = threadIdx.x;
  const int lane = tid & 63;
  const int w = tid >> 6;            // wave's 32-b slice
  const int q = lane >> 4;
  const int lm = lane & 15;
  const int bb = b0 + w * 32;

  const int* idxn = idx + n * GG;

  // per-lane gather offsets for g = ks*32 + q*8 + j (vector idx loads)
  int cof[16];
  #pragma unroll
  for (int ks = 0; ks < 2; ++ks) {
    int4 ca = *(const int4*)(idxn + ks * 32 + q * 8);
    int4 cb = *(const int4*)(idxn + ks * 32 + q * 8 + 4);
    cof[ks * 8 + 0] = ca.x * NB; cof[ks * 8 + 1] = ca.y * NB;
    cof[ks * 8 + 2] = ca.z * NB; cof[ks * 8 + 3] = ca.w * NB;
    cof[ks * 8 + 4] = cb.x * NB; cof[ks * 8 + 5] = cb.y * NB;
    cof[ks * 8 + 6] = cb.z * NB; cof[ks * 8 + 7] = cb.w * NB;
  }

  // A fragments for both m-tiles (rows bb+mi*16+lm)
  bf16x8 afr[2][2];                  // [ks][mi]
  #pragma unroll
  for (int mi = 0; mi < 2; ++mi) {
    const int arow = bb + mi * 16 + lm;
    #pragma unroll
    for (int ks = 0; ks < 2; ++ks) {
      unsigned p[4];
      #pragma unroll
      for (int r = 0; r < 4; ++r) {
        unsigned t0 = xTb[cof[ks * 8 + 2 * r]     + arow];
        unsigned t1 = xTb[cof[ks * 8 + 2 * r + 1] + arow];
        p[r] = t0 | (t1 << 16);
      }
      u32x4 a4; a4.x = p[0]; a4.y = p[1]; a4.z = p[2]; a4.w = p[3];
      afr[ks][mi] = __builtin_bit_cast(bf16x8, a4);
    }
  }

  // B fragments + MFMA: each B-frag feeds both m-tiles
  const u16* wtn = Wt + (size_t)n * (DD * GG);
  f32x4 acc[2][8];                   // [mi][ni]
  #pragma unroll
  for (int mi = 0; mi < 2; ++mi)
    #pragma unroll
    for (int ni = 0; ni < 8; ++ni) acc[mi][ni] = f32x4{0.f, 0.f, 0.f, 0.f};

  #pragma unroll
  for (int ks = 0; ks < 2; ++ks) {
    #pragma unroll
    for (int ni = 0; ni < 8; ++ni) {
      const int d = ni * 16 + lm;
      bf16x8 bfr = *(const bf16x8*)(wtn + d * GG + ks * 32 + q * 8);
      acc[0][ni] = __builtin_amdgcn_mfma_f32_16x16x32_bf16(afr[ks][0], bfr, acc[0][ni], 0, 0, 0);
      acc[1][ni] = __builtin_amdgcn_mfma_f32_16x16x32_bf16(afr[ks][1], bfr, acc[1][ni], 0, 0, 0);
    }
  }

  // epilogue: +bias, LeakyReLU, LN over d (row mi*16+q*4+r in 16 lm-lanes x 8 regs)
  float bv[8], gv[8], tv[8];
  #pragma unroll
  for (int ni = 0; ni < 8; ++ni) {
    const int d = ni * 16 + lm;
    bv[ni] = bias[n * DD + d];
    gv[ni] = gamma[d];
    tv[ni] = beta[d];
  }
  #pragma unroll
  for (int mi = 0; mi < 2; ++mi) {
    #pragma unroll
    for (int r = 0; r < 4; ++r) {
      float h[8];
      float s = 0.f, s2 = 0.f;
      #pragma unroll
      for (int ni = 0; ni < 8; ++ni) {
        float v = acc[mi][ni][r] + bv[ni];
        v = (v >= 0.f) ? v : 0.2f * v;
        h[ni] = v;
        s += v;
        s2 += v * v;
      }
      s  += __shfl_xor(s, 1);  s  += __shfl_xor(s, 2);
      s  += __shfl_xor(s, 4);  s  += __shfl_xor(s, 8);
      s2 += __shfl_xor(s2, 1); s2 += __shfl_xor(s2, 2);
      s2 += __shfl_xor(s2, 4); s2 += __shfl_xor(s2, 8);
      const float mu = s * (1.f / 128.f);
      const float var = s2 * (1.f / 128.f) - mu * mu;
      const float rs = rsqrtf(var + 1e-5f);

      const int brow = bb + mi * 16 + q * 4 + r;
      float* ob = out + ((size_t)brow * NG + n) * DD + lm;
      #pragma unroll
      for (int ni = 0; ni < 8; ++ni)
        __builtin_nontemporal_store((h[ni] - mu) * rs * gv[ni] + tv[ni], ob + ni * 16);
    }
  }
}

extern "C" void kernel_launch(void* const* d_in, const int* in_sizes, int n_in,
                              void* d_out, int out_size, void* d_ws, size_t ws_size,
                              hipStream_t stream) {
  const float* x     = (const float*)d_in[0];
  const int*   idx   = (const int*)d_in[1];
  const float* W     = (const float*)d_in[2];
  const float* bias  = (const float*)d_in[3];
  const float* gamma = (const float*)d_in[4];
  const float* beta  = (const float*)d_in[5];
  float* out = (float*)d_out;

  u16* xTb = (u16*)d_ws;                           // 8192*512 bf16 = 8 MiB
  u16* Wt  = xTb + (size_t)NFEAT * NB;             // 512*128*64 bf16 = 8 MiB

  prep_fused<<<1536, 256, 0, stream>>>(x, xTb, W, Wt);
  lc_mfma<<<2048, 256, 0, stream>>>(xTb, Wt, idx, bias, gamma, beta, out);
}